// Round 4
// baseline (497.582 us; speedup 1.0000x reference)
//
#include <hip/hip_runtime.h>
#include <hip/hip_bf16.h>
#include <math.h>

// Problem constants (from reference): B=4, T=4096, D=1024, hidden=4D.
#define B_SZ 4
#define T_SZ 4096
#define D_SZ 1024
#define H_SZ 4096
#define CHUNK 16
#define NCHUNK (T_SZ / CHUNK)   // 256
#define LN_EPS 1e-5f

using frag8 = __attribute__((ext_vector_type(8))) short;   // 8 x bf16 (4 VGPRs)
using f32x4 = __attribute__((ext_vector_type(4))) float;   // 4 x f32 acc

__device__ __forceinline__ float gelu_exact(float x) {
  return 0.5f * x * (1.0f + erff(x * 0.70710678118654752f));
}

// tanh-form gelu: x*sigmoid(2u) = x - x/(e^{2u}+1), overflow-safe.
__device__ __forceinline__ float gelu_fast(float x) {
  float u2 = 1.5957691216057308f * (x + 0.044715f * x * x * x);
  float e = __expf(u2);
  return x - x * __builtin_amdgcn_rcpf(e + 1.0f);
}

__device__ __forceinline__ unsigned short f2bf(float f) {
  unsigned u = __float_as_uint(f);
  u += 0x7fffu + ((u >> 16) & 1u);   // round-to-nearest-even
  return (unsigned short)(u >> 16);
}

// ---------------------------------------------------------------------------
// LN1 statistics: one block per (b,t) row; fused sum+sumsq reduction.
// ---------------------------------------------------------------------------
__global__ __launch_bounds__(256) void ln_stats(
    const float* __restrict__ x, float2* __restrict__ stats) {
  __shared__ float red[8];
  int tid = threadIdx.x;
  size_t row = (size_t)blockIdx.x * D_SZ;
  float4 v = ((const float4*)(x + row))[tid];
  float s = v.x + v.y + v.z + v.w;
  float q = v.x * v.x + v.y * v.y + v.z * v.z + v.w * v.w;
#pragma unroll
  for (int o = 32; o > 0; o >>= 1) {
    s += __shfl_xor(s, o, 64);
    q += __shfl_xor(q, o, 64);
  }
  int w = tid >> 6;
  if ((tid & 63) == 0) { red[w * 2] = s; red[w * 2 + 1] = q; }
  __syncthreads();
  if (tid == 0) {
    s = red[0] + red[2] + red[4] + red[6];
    q = red[1] + red[3] + red[5] + red[7];
    float mu = s * (1.0f / D_SZ);
    float var = q * (1.0f / D_SZ) - mu * mu;
    float2 st; st.x = mu; st.y = rsqrtf(var + LN_EPS);
    stats[blockIdx.x] = st;
  }
}

// ---------------------------------------------------------------------------
// Kernel A: per (b, time-chunk): LN1(from stats) + gelu + in-chunk cumsum.
// ---------------------------------------------------------------------------
__global__ __launch_bounds__(256) void attn_phase1(
    const float* __restrict__ x, const float2* __restrict__ stats,
    const int* __restrict__ lengths, const float* __restrict__ w1,
    float* __restrict__ partial, float* __restrict__ csum) {
  int b = blockIdx.x >> 8;          // NCHUNK = 256
  int c = blockIdx.x & (NCHUNK - 1);
  int tid = threadIdx.x;
  int len = lengths[b];
  float4 w = ((const float4*)w1)[tid];
  float run0 = 0.f, run1 = 0.f, run2 = 0.f, run3 = 0.f;
#pragma unroll 4
  for (int i = 0; i < CHUNK; ++i) {
    int t = c * CHUNK + i;
    size_t row = ((size_t)b * T_SZ + t) * D_SZ;
    float4 v = ((const float4*)(x + row))[tid];
    float2 st = stats[b * T_SZ + t];
    bool valid = t < len;
    float hx = (v.x - st.x) * st.y * w.x, hy = (v.y - st.x) * st.y * w.y;
    float hz = (v.z - st.x) * st.y * w.z, hw = (v.w - st.x) * st.y * w.w;
    if (valid) {
      run0 += gelu_exact(hx); run1 += gelu_exact(hy);
      run2 += gelu_exact(hz); run3 += gelu_exact(hw);
    }
    float4 p;
    p.x = v.x + hx + (valid ? run0 : 0.f);
    p.y = v.y + hy + (valid ? run1 : 0.f);
    p.z = v.z + hz + (valid ? run2 : 0.f);
    p.w = v.w + hw + (valid ? run3 : 0.f);
    ((float4*)(partial + row))[tid] = p;
  }
  float4 cs; cs.x = run0; cs.y = run1; cs.z = run2; cs.w = run3;
  ((float4*)(csum + ((size_t)b * NCHUNK + c) * D_SZ))[tid] = cs;
}

// ---------------------------------------------------------------------------
// Kernel B: in-place exclusive scan of chunk sums along c, per (b,d).
// ---------------------------------------------------------------------------
__global__ __launch_bounds__(256) void chunk_scan(float* __restrict__ csum) {
  int idx = blockIdx.x * 256 + threadIdx.x;   // 0 .. B*D-1
  int b = idx >> 10;
  int d = idx & (D_SZ - 1);
  float* p = csum + (size_t)b * NCHUNK * D_SZ + d;
  float acc = 0.f;
#pragma unroll 8
  for (int c = 0; c < NCHUNK; ++c) {
    float t = p[(size_t)c * D_SZ];
    p[(size_t)c * D_SZ] = acc;
    acc += t;
  }
}

// ---------------------------------------------------------------------------
// Kernel C: xres = partial + valid*offset (in place), then LN2 -> h2 (bf16).
// ---------------------------------------------------------------------------
__global__ __launch_bounds__(256) void attn_phase2_ln2(
    float* __restrict__ xres, const float* __restrict__ csum,
    const int* __restrict__ lengths, const float* __restrict__ w2,
    unsigned short* __restrict__ h2) {
  __shared__ float red[8];
  int t = blockIdx.x & (T_SZ - 1);
  int b = blockIdx.x >> 12;
  int tid = threadIdx.x;
  bool valid = t < lengths[b];
  int c = t / CHUNK;
  size_t row = ((size_t)b * T_SZ + t) * D_SZ;
  float4 v = ((const float4*)(xres + row))[tid];
  if (valid) {
    float4 o = ((const float4*)(csum + ((size_t)b * NCHUNK + c) * D_SZ))[tid];
    v.x += o.x; v.y += o.y; v.z += o.z; v.w += o.w;
  }
  ((float4*)(xres + row))[tid] = v;
  float s = v.x + v.y + v.z + v.w;
  float q = v.x * v.x + v.y * v.y + v.z * v.z + v.w * v.w;
#pragma unroll
  for (int o = 32; o > 0; o >>= 1) {
    s += __shfl_xor(s, o, 64);
    q += __shfl_xor(q, o, 64);
  }
  int wv = tid >> 6;
  if ((tid & 63) == 0) { red[wv * 2] = s; red[wv * 2 + 1] = q; }
  __syncthreads();
  s = red[0] + red[2] + red[4] + red[6];
  q = red[1] + red[3] + red[5] + red[7];
  float mu = s * (1.0f / D_SZ);
  float var = q * (1.0f / D_SZ) - mu * mu;
  float rstd = rsqrtf(var + LN_EPS);
  float4 w = ((const float4*)w2)[tid];
  ushort4 hq;
  hq.x = f2bf((v.x - mu) * rstd * w.x);
  hq.y = f2bf((v.y - mu) * rstd * w.y);
  hq.z = f2bf((v.z - mu) * rstd * w.z);
  hq.w = f2bf((v.w - mu) * rstd * w.w);
  ((ushort4*)(h2 + row))[tid] = hq;
}

// ---------------------------------------------------------------------------
// Transpose + fp32->bf16 convert: src (R x C) row-major -> dst (C x R) bf16.
// ---------------------------------------------------------------------------
__global__ __launch_bounds__(256) void transpose_f32_to_bf16(
    const float* __restrict__ src, unsigned short* __restrict__ dst,
    int R, int C) {
  __shared__ float tile[32][33];
  int bx = blockIdx.x * 32;   // C base
  int by = blockIdx.y * 32;   // R base
  int tx = threadIdx.x & 31;
  int ty = threadIdx.x >> 5;  // 0..7
#pragma unroll
  for (int i = 0; i < 32; i += 8)
    tile[ty + i][tx] = src[(size_t)(by + ty + i) * C + bx + tx];
  __syncthreads();
#pragma unroll
  for (int i = 0; i < 32; i += 8)
    dst[(size_t)(bx + ty + i) * R + by + tx] = f2bf(tile[tx][ty + i]);
}

// ---------------------------------------------------------------------------
// 256x256 bf16 GEMM, rolling read-ahead (round 4).
//   C[rows,N] = A[rows,K] * Bt[N,K]^T
//   512 threads = 8 waves (2M x 4N); wave tile 128x64; BK=64; nt = K/64.
//   LDS 128 KiB dynamic = dbuf x (A 256x64 + B 256x64) bf16; swizzle as r1.
//   2 phases/tile (A0-half, A1-half), 8 MFMA per tm-group; reads for group
//   tm+1 issued before group tm's MFMAs -> counted lgkm waits mean steady-
//   state MFMA never stalls on LDS. b0/b1 + next-tile's first af pair are
//   post-read at PhY end after vmcnt(6), draining across the barrier.
//   Frag regs: af[2][2]=16 + b0/b1=32 (16 fewer than round 3's af[4][2]).
// ---------------------------------------------------------------------------
__device__ __forceinline__ void gld_lds16(const unsigned short* g,
                                          unsigned short* l) {
  __builtin_amdgcn_global_load_lds(
      (const __attribute__((address_space(1))) unsigned int*)g,
      (__attribute__((address_space(3))) unsigned int*)l, 16, 0, 0);
}

#define GT_TILE (256 * 64)   // ushorts per LDS tile buffer (32 KiB)

// A half-tile h: rows {h*64..+63} U {128+h*64..+63}  (row bit6 == h)
__device__ __forceinline__ void stageA(const unsigned short* A_blk, int K,
                                       unsigned short* as_buf, int h, int k0,
                                       int tid) {
#pragma unroll
  for (int j = 0; j < 2; ++j) {
    int R = j * 128 + h * 64 + (tid >> 3);            // LDS/tile row
    int kc = ((tid & 7) * 8) ^ ((R & 7) << 3);        // inverse-swizzled src k
    gld_lds16(A_blk + (size_t)R * K + k0 + kc,
              as_buf + R * 64 + (tid & 7) * 8);       // linear dest
  }
}

// B half-tile h: rows with bit5 == h within each 64-row group.
__device__ __forceinline__ void stageB(const unsigned short* B_blk, int K,
                                       unsigned short* bs_buf, int h, int k0,
                                       int tid) {
  int lr = tid >> 3;   // 0..63
#pragma unroll
  for (int j = 0; j < 2; ++j) {
    int R = j * 128 + (lr >> 5) * 64 + h * 32 + (lr & 31);
    int kc = ((tid & 7) * 8) ^ ((R & 7) << 3);
    gld_lds16(B_blk + (size_t)R * K + k0 + kc,
              bs_buf + R * 64 + (tid & 7) * 8);
  }
}

// One tm-pair of A fragments (2 x ds_read_b128), compile-time tm/mh.
__device__ __forceinline__ void read_a_pair(const unsigned short* base,
                                            frag8 (&dst)[2], int mh, int tm,
                                            int wm, int r16, int quad) {
#pragma unroll
  for (int kk = 0; kk < 2; ++kk) {
    int r = wm * 128 + mh * 64 + tm * 16 + r16;
    int cb = (kk * 64 + quad * 16) ^ ((r16 & 7) << 4);   // swizzled byte col
    dst[kk] = *(const frag8*)(base + r * 64 + (cb >> 1));
  }
}

__device__ __forceinline__ void load_bfrag(const unsigned short* base,
                                           frag8 (&dst)[2][2], int nh, int wn,
                                           int r16, int quad) {
#pragma unroll
  for (int tn = 0; tn < 2; ++tn)
#pragma unroll
    for (int kk = 0; kk < 2; ++kk) {
      int r = wn * 64 + nh * 32 + tn * 16 + r16;
      int cb = (kk * 64 + quad * 16) ^ ((r16 & 7) << 4);
      dst[tn][kk] = *(const frag8*)(base + r * 64 + (cb >> 1));
    }
}

// 4 MFMAs: one tm-row x one n-half, acc[mh*4+tm][nh*2+tn].
__device__ __forceinline__ void mfma_g(f32x4 (&acc)[8][4], const frag8 (&a)[2],
                                       const frag8 (&b)[2][2], int mh, int tm,
                                       int nh) {
#pragma unroll
  for (int kk = 0; kk < 2; ++kk)
#pragma unroll
    for (int tn = 0; tn < 2; ++tn)
      acc[mh * 4 + tm][nh * 2 + tn] =
          __builtin_amdgcn_mfma_f32_16x16x32_bf16(
              a[kk], b[tn][kk], acc[mh * 4 + tm][nh * 2 + tn], 0, 0, 0);
}

// Raw barrier (no implicit vmcnt/lgkm drain) + compiler fence both sides.
#define GBAR()                          \
  do {                                  \
    asm volatile("" ::: "memory");      \
    __builtin_amdgcn_s_barrier();       \
    asm volatile("" ::: "memory");      \
  } while (0)

__global__ __launch_bounds__(512, 2) void gemm256_bt(
    const unsigned short* __restrict__ A, const unsigned short* __restrict__ Bt,
    int N, int K, int gx,
    const float* __restrict__ resid, float* __restrict__ outf,
    unsigned short* __restrict__ outb, int epi) {
  extern __shared__ unsigned short smem[];
  unsigned short* As = smem;                 // [2][256][64]
  unsigned short* Bs = smem + 2 * GT_TILE;   // [2][256][64]

  // XCD-aware bijective block swizzle (grid % 8 == 0 in our launches).
  int orig = blockIdx.x, nwg = gridDim.x;
  int wg = orig;
  if ((nwg & 7) == 0) wg = (orig & 7) * (nwg >> 3) + (orig >> 3);
  int bx = wg % gx, by = wg / gx;
  int bm = by * 256, bn = bx * 256;

  int tid = threadIdx.x;
  int lane = tid & 63, wave = tid >> 6;
  int wm = wave >> 2, wn = wave & 3;         // 2 x 4 wave grid
  int quad = lane >> 4, r16 = lane & 15;

  const unsigned short* A_blk = A + (size_t)bm * K;
  const unsigned short* B_blk = Bt + (size_t)bn * K;
  int nt = K >> 6;

  f32x4 acc[8][4] = {};
  frag8 af[2][2];            // rolling A fragments (one tm-pair + lookahead)
  frag8 b0[2][2], b1[2][2];  // B-half fragments (whole-tile resident)

  // Prologue: tile0 full (8 loads) + tile1 {A0,B0,B1} (6); wait oldest 8.
  stageA(A_blk, K, As, 0, 0, tid);
  stageA(A_blk, K, As, 1, 0, tid);
  stageB(B_blk, K, Bs, 0, 0, tid);
  stageB(B_blk, K, Bs, 1, 0, tid);
  if (nt > 1) {
    stageA(A_blk, K, As + GT_TILE, 0, 64, tid);   // A0(1)
    stageB(B_blk, K, Bs + GT_TILE, 0, 64, tid);   // B0(1)
    stageB(B_blk, K, Bs + GT_TILE, 1, 64, tid);   // B1(1)
    asm volatile("s_waitcnt vmcnt(6)" ::: "memory");
  } else {
    asm volatile("s_waitcnt vmcnt(0)" ::: "memory");
  }
  GBAR();
  // Pre-read tile0 operands that steady state post-reads at PhY end.
  read_a_pair(As, af[0], 0, 0, wm, r16, quad);   // A0(0), tm=0
  load_bfrag(Bs, b0, 0, wn, r16, quad);          // B0(0)
  load_bfrag(Bs, b1, 1, wn, r16, quad);          // B1(0)

  // Steady-state invariant at tile start: 6 loads in flight =
  // {A0,B0,B1}(t+1). Tile t issues {A1(t+1)} at PhX and {A0,B0,B1}(t+2)
  // at PhY; vmcnt(6) at PhY completes the 8 oldest = full tile t+1.
  for (int t = 0; t < nt; ++t) {
    unsigned short* As_c = As + (t & 1) * GT_TILE;
    unsigned short* Bs_c = Bs + (t & 1) * GT_TILE;
    unsigned short* As_n = As + ((t + 1) & 1) * GT_TILE;
    unsigned short* Bs_n = Bs + ((t + 1) & 1) * GT_TILE;
    bool p1 = (t + 1 < nt), p2 = (t + 2 < nt);

    // ---- PhX: A0-half. Stage A1(t+1)->n; rolling tm-groups (q00+q01).
    if (p1) stageA(A_blk, K, As_n, 1, (t + 1) * 64, tid);
    GBAR();
    __builtin_amdgcn_s_setprio(1);
#pragma unroll
    for (int tm = 0; tm < 4; ++tm) {
      if (tm < 3) read_a_pair(As_c, af[(tm + 1) & 1], 0, tm + 1, wm, r16, quad);
      mfma_g(acc, af[tm & 1], b0, 0, tm, 0);   // q00
      mfma_g(acc, af[tm & 1], b1, 0, tm, 1);   // q01
    }
    __builtin_amdgcn_s_setprio(0);
    GBAR();

    // ---- PhY: A1-half. Pre-read af[0]<-A1(c) (region stable; staged at
    //      t-1 PhX, resident since t-1 PhY vmcnt). Stage {A0,B0,B1}(t+2)->c
    //      (all three regions' readers lgkm-drained in earlier phases);
    //      vmcnt(6) completes tile t+1. Rolling tm-groups (q11+q10), then
    //      post-read next tile's b0/b1/af[0] (drain across the barrier).
    read_a_pair(As_c, af[0], 1, 0, wm, r16, quad);
    if (p2) {
      stageA(A_blk, K, As_c, 0, (t + 2) * 64, tid);
      stageB(B_blk, K, Bs_c, 0, (t + 2) * 64, tid);
      stageB(B_blk, K, Bs_c, 1, (t + 2) * 64, tid);
      asm volatile("s_waitcnt vmcnt(6)" ::: "memory");
    } else {
      asm volatile("s_waitcnt vmcnt(0)" ::: "memory");
    }
    GBAR();
    __builtin_amdgcn_s_setprio(1);
#pragma unroll
    for (int tm = 0; tm < 4; ++tm) {
      if (tm < 3) read_a_pair(As_c, af[(tm + 1) & 1], 1, tm + 1, wm, r16, quad);
      mfma_g(acc, af[tm & 1], b1, 1, tm, 1);   // q11
      mfma_g(acc, af[tm & 1], b0, 1, tm, 0);   // q10
    }
    __builtin_amdgcn_s_setprio(0);
    if (p1) {
      // WAR deps on b0/b1/af keep these after the last MFMA group.
      load_bfrag(Bs_n, b0, 0, wn, r16, quad);          // B0(t+1)
      load_bfrag(Bs_n, b1, 1, wn, r16, quad);          // B1(t+1)
      read_a_pair(As_n, af[0], 0, 0, wm, r16, quad);   // A0(t+1), tm=0
    }
    GBAR();
  }

  // Epilogue. C row = bm + wm*128 + mf*16 + quad*4 + r; col = bn + wn*64 +
  // nf*16 + r16 (C/D layout: col=lane&15, row=(lane>>4)*4+reg).
  if (epi == 0) {
#pragma unroll
    for (int mf = 0; mf < 8; ++mf) {
#pragma unroll
      for (int nf = 0; nf < 4; ++nf) {
        int gm0 = bm + wm * 128 + mf * 16 + quad * 4;
        int gn = bn + wn * 64 + nf * 16 + r16;
#pragma unroll
        for (int r = 0; r < 4; ++r)
          outb[(size_t)(gm0 + r) * N + gn] = f2bf(gelu_fast(acc[mf][nf][r]));
      }
    }
  } else {
#pragma unroll
    for (int mf = 0; mf < 8; ++mf) {
#pragma unroll
      for (int nf = 0; nf < 4; ++nf) {
        int gm0 = bm + wm * 128 + mf * 16 + quad * 4;
        int gn = bn + wn * 64 + nf * 16 + r16;
#pragma unroll
        for (int r = 0; r < 4; ++r)
          outf[(size_t)(gm0 + r) * N + gn] =
              resid[(size_t)(gm0 + r) * N + gn] + acc[mf][nf][r];
      }
    }
  }
}

// ---------------------------------------------------------------------------
extern "C" void kernel_launch(void* const* d_in, const int* in_sizes, int n_in,
                              void* d_out, int out_size, void* d_ws,
                              size_t ws_size, hipStream_t stream) {
  const float* x = (const float*)d_in[0];
  const int* lengths = (const int*)d_in[1];
  const float* ln1_w = (const float*)d_in[2];
  const float* ln2_w = (const float*)d_in[3];
  const float* Wfc = (const float*)d_in[4];
  const float* Wproj = (const float*)d_in[5];
  float* out = (float*)d_out;   // doubles as the xres residual-stream buffer

  // One-time: allow 128 KiB dynamic LDS for the 256^2 GEMM.
  static bool lds_cfg = false;
  if (!lds_cfg) {
    hipFuncSetAttribute((const void*)gemm256_bt,
                        hipFuncAttributeMaxDynamicSharedMemorySize, 131072);
    lds_cfg = true;
  }

  // Workspace layout — fixed ~52 MiB + act slice sized from ws_size.
  char* ws = (char*)d_ws;
  size_t off = 0;
  float2* stats = (float2*)(ws + off);
  off += (size_t)B_SZ * T_SZ * sizeof(float2);                  // 128 KiB
  float* csum = (float*)(ws + off);
  off += (size_t)B_SZ * NCHUNK * D_SZ * sizeof(float);          // 4 MiB
  unsigned short* wfcb = (unsigned short*)(ws + off);
  off += (size_t)D_SZ * H_SZ * sizeof(unsigned short);          // 8 MiB
  unsigned short* wprojb = (unsigned short*)(ws + off);
  off += (size_t)H_SZ * D_SZ * sizeof(unsigned short);          // 8 MiB
  unsigned short* h2 = (unsigned short*)(ws + off);
  off += (size_t)B_SZ * T_SZ * D_SZ * sizeof(unsigned short);   // 32 MiB
  unsigned short* act = (unsigned short*)(ws + off);            // slice buffer

  const int M = B_SZ * T_SZ;                       // 16384
  const size_t tileBytes = 256ull * H_SZ * sizeof(unsigned short);  // 2 MiB
  size_t avail = (ws_size > off) ? (ws_size - off) : 0;
  int sliceTiles = (int)(avail / tileBytes);
  if (sliceTiles < 1) sliceTiles = 1;              // last-resort (ws too small)
  int sliceM = sliceTiles * 256;
  if (sliceM > M) sliceM = M;

  ln_stats<<<B_SZ * T_SZ, 256, 0, stream>>>(x, stats);
  attn_phase1<<<B_SZ * NCHUNK, 256, 0, stream>>>(x, stats, lengths, ln1_w,
                                                 out, csum);
  chunk_scan<<<(B_SZ * D_SZ) / 256, 256, 0, stream>>>(csum);
  attn_phase2_ln2<<<B_SZ * T_SZ, 256, 0, stream>>>(out, csum, lengths, ln2_w, h2);
  transpose_f32_to_bf16<<<dim3(H_SZ / 32, D_SZ / 32), 256, 0, stream>>>(
      Wfc, wfcb, D_SZ, H_SZ);
  transpose_f32_to_bf16<<<dim3(D_SZ / 32, H_SZ / 32), 256, 0, stream>>>(
      Wproj, wprojb, H_SZ, D_SZ);

  for (int m0 = 0; m0 < M; m0 += sliceM) {
    int rows = (M - m0 < sliceM) ? (M - m0) : sliceM;
    int r1 = rows / 256;
    // act = bf16(gelu(h2[m0:m0+rows] @ Wfc))       grid = 16*r1 (%8==0)
    gemm256_bt<<<dim3((H_SZ / 256) * r1), 512, 131072, stream>>>(
        h2 + (size_t)m0 * D_SZ, wfcb, H_SZ, D_SZ, H_SZ / 256,
        nullptr, nullptr, act, 0);
    // out[m0:m0+rows] += act @ Wproj               grid = 4*r1
    gemm256_bt<<<dim3((D_SZ / 256) * r1), 512, 131072, stream>>>(
        act, wprojb, D_SZ, H_SZ, D_SZ / 256,
        out + (size_t)m0 * D_SZ, out + (size_t)m0 * D_SZ, nullptr, 1);
  }
}

// Round 5
// 458.443 us; speedup vs baseline: 1.0854x; 1.0854x over previous
//
#include <hip/hip_runtime.h>
#include <hip/hip_bf16.h>
#include <math.h>

// Problem constants (from reference): B=4, T=4096, D=1024, hidden=4D.
#define B_SZ 4
#define T_SZ 4096
#define D_SZ 1024
#define H_SZ 4096
#define CHUNK 16
#define NCHUNK (T_SZ / CHUNK)   // 256
#define NSEG 8
#define SEGC (NCHUNK / NSEG)    // 32 chunks per segment
#define LN_EPS 1e-5f

using frag8 = __attribute__((ext_vector_type(8))) short;   // 8 x bf16 (4 VGPRs)
using f32x4 = __attribute__((ext_vector_type(4))) float;   // 4 x f32 acc

__device__ __forceinline__ float gelu_exact(float x) {
  return 0.5f * x * (1.0f + erff(x * 0.70710678118654752f));
}

// tanh-form gelu: x*sigmoid(2u) = x - x/(e^{2u}+1), overflow-safe.
__device__ __forceinline__ float gelu_fast(float x) {
  float u2 = 1.5957691216057308f * (x + 0.044715f * x * x * x);
  float e = __expf(u2);
  return x - x * __builtin_amdgcn_rcpf(e + 1.0f);
}

__device__ __forceinline__ unsigned short f2bf(float f) {
  unsigned u = __float_as_uint(f);
  u += 0x7fffu + ((u >> 16) & 1u);   // round-to-nearest-even
  return (unsigned short)(u >> 16);
}

// ---------------------------------------------------------------------------
// Kernel A (LN1 stats fused in): per (b, time-chunk): per-row block reduction
// for mu/rstd, then LN1 + gelu + in-chunk cumsum. x is read exactly once.
// ---------------------------------------------------------------------------
__global__ __launch_bounds__(256) void attn_phase1(
    const float* __restrict__ x, const int* __restrict__ lengths,
    const float* __restrict__ w1, float* __restrict__ partial,
    float* __restrict__ csum) {
  __shared__ float red[8];
  int b = blockIdx.x >> 8;          // NCHUNK = 256
  int c = blockIdx.x & (NCHUNK - 1);
  int tid = threadIdx.x;
  int len = lengths[b];
  float4 w = ((const float4*)w1)[tid];
  float run0 = 0.f, run1 = 0.f, run2 = 0.f, run3 = 0.f;
  for (int i = 0; i < CHUNK; ++i) {
    int t = c * CHUNK + i;
    size_t row = ((size_t)b * T_SZ + t) * D_SZ;
    float4 v = ((const float4*)(x + row))[tid];
    float s = v.x + v.y + v.z + v.w;
    float q = v.x * v.x + v.y * v.y + v.z * v.z + v.w * v.w;
#pragma unroll
    for (int o = 32; o > 0; o >>= 1) {
      s += __shfl_xor(s, o, 64);
      q += __shfl_xor(q, o, 64);
    }
    if ((tid & 63) == 0) { red[(tid >> 6) * 2] = s; red[(tid >> 6) * 2 + 1] = q; }
    __syncthreads();
    s = red[0] + red[2] + red[4] + red[6];
    q = red[1] + red[3] + red[5] + red[7];
    __syncthreads();   // red reusable next row
    float mu = s * (1.0f / D_SZ);
    float var = q * (1.0f / D_SZ) - mu * mu;
    float rstd = rsqrtf(var + LN_EPS);
    bool valid = t < len;
    float hx = (v.x - mu) * rstd * w.x, hy = (v.y - mu) * rstd * w.y;
    float hz = (v.z - mu) * rstd * w.z, hw = (v.w - mu) * rstd * w.w;
    if (valid) {
      run0 += gelu_exact(hx); run1 += gelu_exact(hy);
      run2 += gelu_exact(hz); run3 += gelu_exact(hw);
    }
    float4 p;
    p.x = v.x + hx + (valid ? run0 : 0.f);
    p.y = v.y + hy + (valid ? run1 : 0.f);
    p.z = v.z + hz + (valid ? run2 : 0.f);
    p.w = v.w + hw + (valid ? run3 : 0.f);
    ((float4*)(partial + row))[tid] = p;
  }
  float4 cs; cs.x = run0; cs.y = run1; cs.z = run2; cs.w = run3;
  ((float4*)(csum + ((size_t)b * NCHUNK + c) * D_SZ))[tid] = cs;
}

// ---------------------------------------------------------------------------
// Kernel B1: per (b,seg,dq): in-place exclusive scan of 32 chunk sums within
// the segment + write segment total. 128 blocks, serial depth 32 (was 256
// with 16 blocks).
// ---------------------------------------------------------------------------
__global__ __launch_bounds__(256) void seg_scan(float* __restrict__ csum,
                                                float* __restrict__ segsum) {
  int blk = blockIdx.x;   // b*32 + seg*4 + dq
  int b = blk >> 5, seg = (blk >> 2) & 7, dq = blk & 3;
  int d = dq * 256 + threadIdx.x;
  float* p = csum + ((size_t)b * NCHUNK + seg * SEGC) * D_SZ + d;
  float acc = 0.f;
#pragma unroll 8
  for (int j = 0; j < SEGC; ++j) {
    float v = p[(size_t)j * D_SZ];
    p[(size_t)j * D_SZ] = acc;
    acc += v;
  }
  segsum[((size_t)b * NSEG + seg) * D_SZ + d] = acc;
}

// ---------------------------------------------------------------------------
// Kernel B2: add exclusive segment-offset to all chunks in the segment.
// ---------------------------------------------------------------------------
__global__ __launch_bounds__(256) void seg_apply(
    float* __restrict__ csum, const float* __restrict__ segsum) {
  int blk = blockIdx.x;   // b*32 + seg*4 + dq
  int b = blk >> 5, seg = (blk >> 2) & 7, dq = blk & 3;
  if (seg == 0) return;
  int d = dq * 256 + threadIdx.x;
  float off = 0.f;
  for (int s = 0; s < NSEG; ++s) {
    float v = segsum[((size_t)b * NSEG + s) * D_SZ + d];
    if (s < seg) off += v;
  }
  float* p = csum + ((size_t)b * NCHUNK + seg * SEGC) * D_SZ + d;
#pragma unroll 8
  for (int j = 0; j < SEGC; ++j) p[(size_t)j * D_SZ] += off;
}

// ---------------------------------------------------------------------------
// Kernel C: xres = partial + valid*offset (in place), then LN2 -> h2 (bf16).
// ---------------------------------------------------------------------------
__global__ __launch_bounds__(256) void attn_phase2_ln2(
    float* __restrict__ xres, const float* __restrict__ csum,
    const int* __restrict__ lengths, const float* __restrict__ w2,
    unsigned short* __restrict__ h2) {
  __shared__ float red[8];
  int t = blockIdx.x & (T_SZ - 1);
  int b = blockIdx.x >> 12;
  int tid = threadIdx.x;
  bool valid = t < lengths[b];
  int c = t / CHUNK;
  size_t row = ((size_t)b * T_SZ + t) * D_SZ;
  float4 v = ((const float4*)(xres + row))[tid];
  if (valid) {
    float4 o = ((const float4*)(csum + ((size_t)b * NCHUNK + c) * D_SZ))[tid];
    v.x += o.x; v.y += o.y; v.z += o.z; v.w += o.w;
  }
  ((float4*)(xres + row))[tid] = v;
  float s = v.x + v.y + v.z + v.w;
  float q = v.x * v.x + v.y * v.y + v.z * v.z + v.w * v.w;
#pragma unroll
  for (int o = 32; o > 0; o >>= 1) {
    s += __shfl_xor(s, o, 64);
    q += __shfl_xor(q, o, 64);
  }
  int wv = tid >> 6;
  if ((tid & 63) == 0) { red[wv * 2] = s; red[wv * 2 + 1] = q; }
  __syncthreads();
  s = red[0] + red[2] + red[4] + red[6];
  q = red[1] + red[3] + red[5] + red[7];
  float mu = s * (1.0f / D_SZ);
  float var = q * (1.0f / D_SZ) - mu * mu;
  float rstd = rsqrtf(var + LN_EPS);
  float4 w = ((const float4*)w2)[tid];
  ushort4 hq;
  hq.x = f2bf((v.x - mu) * rstd * w.x);
  hq.y = f2bf((v.y - mu) * rstd * w.y);
  hq.z = f2bf((v.z - mu) * rstd * w.z);
  hq.w = f2bf((v.w - mu) * rstd * w.w);
  ((ushort4*)(h2 + row))[tid] = hq;
}

// ---------------------------------------------------------------------------
// Transpose + fp32->bf16 convert: src (R x C) row-major -> dst (C x R) bf16.
// ---------------------------------------------------------------------------
__global__ __launch_bounds__(256) void transpose_f32_to_bf16(
    const float* __restrict__ src, unsigned short* __restrict__ dst,
    int R, int C) {
  __shared__ float tile[32][33];
  int bx = blockIdx.x * 32;   // C base
  int by = blockIdx.y * 32;   // R base
  int tx = threadIdx.x & 31;
  int ty = threadIdx.x >> 5;  // 0..7
#pragma unroll
  for (int i = 0; i < 32; i += 8)
    tile[ty + i][tx] = src[(size_t)(by + ty + i) * C + bx + tx];
  __syncthreads();
#pragma unroll
  for (int i = 0; i < 32; i += 8)
    dst[(size_t)(bx + ty + i) * R + by + tx] = f2bf(tile[tx][ty + i]);
}

// ---------------------------------------------------------------------------
// 256x256 bf16 GEMM, round-3 schedule + HOISTED ADDRESSING (round 5).
//   All ds_read addresses = 4 loop-invariant base VGPRs + compile-time
//   immediate offsets; dbuf parity is a compile-time immediate via K-loop
//   unroll x2 (nt even: K % 128 == 0). Staging = 2 base pointers + scalar
//   stream offsets. Target: kill the 32% VALUBusy (address remat at the
//   VGPR cap) that made rounds 1/3/4 schedule-invariant at ~35% MfmaUtil.
//   LDS map (bytes): A buf0 [0,32K), A buf1 [32K,64K), B buf0 [64K,96K),
//   B buf1 [96K,128K). Row stride 128 B. Swizzle: 16B chunk ^= (row&7)<<4,
//   inverse-applied on the global source, forward on ds_read (involution).
// ---------------------------------------------------------------------------
#define GT_TILE (256 * 64)   // ushorts per LDS tile buffer (32 KiB)

#define GLD16(gsrc, ldsoff)                                                   \
  __builtin_amdgcn_global_load_lds(                                           \
      (const __attribute__((address_space(1))) unsigned int*)(gsrc),          \
      (__attribute__((address_space(3))) unsigned int*)(smc + (ldsoff)), 16,  \
      0, 0)

// A half-tile h -> rows {h*64..+63} U {128+h*64..+63}; global src row
// (tid>>3) + h*64 + j*128, k-col pre-swizzled; LDS dest linear.
#define STAGE_A(h, DP, k0e)                                                   \
  do {                                                                        \
    GLD16(gA + (size_t)((h) * 64) * K + (k0e),                                \
          aW + (h) * 8192 + (DP) * 32768);                                    \
    GLD16(gA + (size_t)((h) * 64 + 128) * K + (k0e),                          \
          aW + (h) * 8192 + 16384 + (DP) * 32768);                            \
  } while (0)

// B half-tile h -> rows with bit5==h in each 64-row group.
#define STAGE_B(h, DP, k0e)                                                   \
  do {                                                                        \
    GLD16(gB + (size_t)((h) * 32) * K + (k0e),                                \
          bW + (h) * 4096 + (DP) * 32768);                                    \
    GLD16(gB + (size_t)((h) * 32 + 128) * K + (k0e),                          \
          bW + (h) * 4096 + 16384 + (DP) * 32768);                            \
  } while (0)

// A fragments, m-half MH: addr = base[kk] + (CUR + MH*8192 + tm*2048).
template <int CUR, int MH>
__device__ __forceinline__ void rd_af(const char* smc, int aB0, int aB1,
                                      frag8 (&af)[4][2]) {
#pragma unroll
  for (int tm = 0; tm < 4; ++tm) {
    af[tm][0] = *(const frag8*)(smc + aB0 + (CUR + MH * 8192 + tm * 2048));
    af[tm][1] = *(const frag8*)(smc + aB1 + (CUR + MH * 8192 + tm * 2048));
  }
}

// B fragments, n-half NH: addr = base[kk] + (CUR + NH*4096 + tn*2048).
template <int CUR, int NH>
__device__ __forceinline__ void rd_bf(const char* smc, int bB0, int bB1,
                                      frag8 (&bf)[2][2]) {
#pragma unroll
  for (int tn = 0; tn < 2; ++tn) {
    bf[tn][0] = *(const frag8*)(smc + bB0 + (CUR + NH * 4096 + tn * 2048));
    bf[tn][1] = *(const frag8*)(smc + bB1 + (CUR + NH * 4096 + tn * 2048));
  }
}

template <int MH, int NH>
__device__ __forceinline__ void mfma_q(f32x4 (&acc)[8][4],
                                       const frag8 (&a)[4][2],
                                       const frag8 (&b)[2][2]) {
#pragma unroll
  for (int kk = 0; kk < 2; ++kk)
#pragma unroll
    for (int tm = 0; tm < 4; ++tm)
#pragma unroll
      for (int tn = 0; tn < 2; ++tn)
        acc[MH * 4 + tm][NH * 2 + tn] =
            __builtin_amdgcn_mfma_f32_16x16x32_bf16(
                a[tm][kk], b[tn][kk], acc[MH * 4 + tm][NH * 2 + tn], 0, 0, 0);
}

// Raw barrier (no implicit vmcnt/lgkm drain) + compiler fence both sides.
#define GBAR()                          \
  do {                                  \
    asm volatile("" ::: "memory");      \
    __builtin_amdgcn_s_barrier();       \
    asm volatile("" ::: "memory");      \
  } while (0)

// One K-tile, round-3 phase order (q00,q01,q11,q10). CURB/NXTB = byte offset
// of current/next dbuf (0 or 32768), CURP/NXTP = parity bit (0/1) — all
// compile-time. Lifetime/vmcnt accounting identical to round 3.
#define TILE_BODY(t, CURB, CURP, NXTB, NXTP)                                  \
  do {                                                                        \
    bool p1 = (t) + 1 < nt, p2 = (t) + 2 < nt;                                \
    /* PH0: af <- A0(cur); stage A1(t+1)->nxt; q00(af,b0). */                 \
    rd_af<CURB, 0>(smc, aB0, aB1, af);                                        \
    if (p1) STAGE_A(1, NXTP, ((t) + 1) * 64);                                 \
    GBAR();                                                                   \
    __builtin_amdgcn_s_setprio(1);                                            \
    mfma_q<0, 0>(acc, af, b0);                                                \
    __builtin_amdgcn_s_setprio(0);                                            \
    GBAR();                                                                   \
    /* PH1: b1 <- B1(cur); stage A0(t+2)->cur (dead since PH0); q01. */       \
    rd_bf<CURB, 1>(smc, bB0, bB1, b1);                                        \
    if (p2) STAGE_A(0, CURP, ((t) + 2) * 64);                                 \
    GBAR();                                                                   \
    __builtin_amdgcn_s_setprio(1);                                            \
    mfma_q<0, 1>(acc, af, b1);                                                \
    __builtin_amdgcn_s_setprio(0);                                            \
    GBAR();                                                                   \
    /* PH2: af <- A1(cur); stage B0(t+2)->cur (dead since prev PH3); q11. */  \
    rd_af<CURB, 1>(smc, aB0, aB1, af);                                        \
    if (p2) STAGE_B(0, CURP, ((t) + 2) * 64);                                 \
    GBAR();                                                                   \
    __builtin_amdgcn_s_setprio(1);                                            \
    mfma_q<1, 1>(acc, af, b1);                                                \
    __builtin_amdgcn_s_setprio(0);                                            \
    GBAR();                                                                   \
    /* PH3: stage B1(t+2)->cur (dead since PH1); vmcnt(6) completes t+1;      \
       q10; post-read b0 <- B0(nxt) drains across the barrier. */             \
    if (p2) {                                                                 \
      STAGE_B(1, CURP, ((t) + 2) * 64);                                       \
      asm volatile("s_waitcnt vmcnt(6)" ::: "memory");                        \
    } else {                                                                  \
      asm volatile("s_waitcnt vmcnt(0)" ::: "memory");                        \
    }                                                                         \
    GBAR();                                                                   \
    __builtin_amdgcn_s_setprio(1);                                            \
    mfma_q<1, 0>(acc, af, b0);                                                \
    __builtin_amdgcn_s_setprio(0);                                            \
    if (p1) rd_bf<NXTB, 0>(smc, bB0, bB1, b0);                                \
    GBAR();                                                                   \
  } while (0)

__global__ __launch_bounds__(512, 2) void gemm256_bt(
    const unsigned short* __restrict__ A, const unsigned short* __restrict__ Bt,
    int N, int K, int gx,
    const float* __restrict__ resid, float* __restrict__ outf,
    unsigned short* __restrict__ outb, int epi) {
  extern __shared__ char smc[];   // 128 KiB

  // XCD-aware bijective block swizzle (grid % 8 == 0 in our launches).
  int orig = blockIdx.x, nwg = gridDim.x;
  int wg = orig;
  if ((nwg & 7) == 0) wg = (orig & 7) * (nwg >> 3) + (orig >> 3);
  int bx = wg % gx, by = wg / gx;
  int bm = by * 256, bn = bx * 256;

  int tid = threadIdx.x;
  int lane = tid & 63, wave = tid >> 6;
  int wm = wave >> 2, wn = wave & 3;         // 2 x 4 wave grid
  int quad = lane >> 4, r16 = lane & 15;

  const unsigned short* A_blk = A + (size_t)bm * K;
  const unsigned short* B_blk = Bt + (size_t)bn * K;
  int nt = K >> 6;   // even for K in {1024, 4096}

  // ---- LDS read bases (bytes), loop-invariant. Row r byte-addr = r*128 +
  // ((kk*64 + quad*16) ^ ((r&7)<<4)); r&7 == r16&7 for all frag rows.
  int swz = (r16 & 7) << 4;
  int aB0 = wm * 16384 + r16 * 128 + ((quad * 16) ^ swz);
  int aB1 = wm * 16384 + r16 * 128 + ((64 + quad * 16) ^ swz);
  int bB0 = 65536 + wn * 8192 + r16 * 128 + ((quad * 16) ^ swz);
  int bB1 = 65536 + wn * 8192 + r16 * 128 + ((64 + quad * 16) ^ swz);

  // ---- staging bases, loop-invariant. Global src pre-swizzled (involution
  // with the read-side XOR); LDS dest linear (wave-contiguous 1024B).
  int arow = tid >> 3;                                  // 0..63
  int kc = ((tid & 7) * 8) ^ ((arow & 7) << 3);         // elements
  const unsigned short* gA = A_blk + (size_t)arow * K + kc;
  int browl = (arow >> 5) * 64 + (arow & 31);           // B low row
  const unsigned short* gB = B_blk + (size_t)browl * K + kc;
  int aW = arow * 128 + (tid & 7) * 16;                 // LDS dest bytes
  int bW = 65536 + browl * 128 + (tid & 7) * 16;

  f32x4 acc[8][4] = {};
  frag8 af[4][2];            // A-half fragments (single buffer, reused)
  frag8 b0[2][2], b1[2][2];  // B-half fragments

  // Prologue: tile0 full (8 loads) + tile1 {A0,B0,B1} (6); wait oldest 8.
  STAGE_A(0, 0, 0);
  STAGE_A(1, 0, 0);
  STAGE_B(0, 0, 0);
  STAGE_B(1, 0, 0);
  if (nt > 1) {
    STAGE_A(0, 1, 64);
    STAGE_B(0, 1, 64);
    STAGE_B(1, 1, 64);
    asm volatile("s_waitcnt vmcnt(6)" ::: "memory");
  } else {
    asm volatile("s_waitcnt vmcnt(0)" ::: "memory");
  }
  GBAR();
  rd_bf<0, 0>(smc, bB0, bB1, b0);   // B0 of tile 0

  // Steady-state invariant at tile start: 6 loads in flight = {A0,B0,B1}(t+1).
  // Tile t issues {A1(t+1), A0(t+2), B0(t+2), B1(t+2)}; vmcnt(6) at PH3
  // completes the 8 oldest = full tile t+1. Unroll x2 -> dbuf parity is a
  // compile-time immediate.
  for (int t = 0; t < nt; t += 2) {
    TILE_BODY(t, 0, 0, 32768, 1);
    TILE_BODY(t + 1, 32768, 1, 0, 0);
  }

  // Epilogue. C row = bm + wm*128 + mf*16 + quad*4 + r; col = bn + wn*64 +
  // nf*16 + r16 (C/D layout: col=lane&15, row=(lane>>4)*4+reg).
  if (epi == 0) {
#pragma unroll
    for (int mf = 0; mf < 8; ++mf) {
#pragma unroll
      for (int nf = 0; nf < 4; ++nf) {
        int gm0 = bm + wm * 128 + mf * 16 + quad * 4;
        int gn = bn + wn * 64 + nf * 16 + r16;
#pragma unroll
        for (int r = 0; r < 4; ++r)
          outb[(size_t)(gm0 + r) * N + gn] = f2bf(gelu_fast(acc[mf][nf][r]));
      }
    }
  } else {
#pragma unroll
    for (int mf = 0; mf < 8; ++mf) {
#pragma unroll
      for (int nf = 0; nf < 4; ++nf) {
        int gm0 = bm + wm * 128 + mf * 16 + quad * 4;
        int gn = bn + wn * 64 + nf * 16 + r16;
#pragma unroll
        for (int r = 0; r < 4; ++r)
          outf[(size_t)(gm0 + r) * N + gn] =
              resid[(size_t)(gm0 + r) * N + gn] + acc[mf][nf][r];
      }
    }
  }
}

// ---------------------------------------------------------------------------
extern "C" void kernel_launch(void* const* d_in, const int* in_sizes, int n_in,
                              void* d_out, int out_size, void* d_ws,
                              size_t ws_size, hipStream_t stream) {
  const float* x = (const float*)d_in[0];
  const int* lengths = (const int*)d_in[1];
  const float* ln1_w = (const float*)d_in[2];
  const float* ln2_w = (const float*)d_in[3];
  const float* Wfc = (const float*)d_in[4];
  const float* Wproj = (const float*)d_in[5];
  float* out = (float*)d_out;   // doubles as the xres residual-stream buffer

  // One-time: allow 128 KiB dynamic LDS for the 256^2 GEMM.
  static bool lds_cfg = false;
  if (!lds_cfg) {
    hipFuncSetAttribute((const void*)gemm256_bt,
                        hipFuncAttributeMaxDynamicSharedMemorySize, 131072);
    lds_cfg = true;
  }

  // Workspace layout — fixed ~52 MiB + act slice sized from ws_size.
  char* ws = (char*)d_ws;
  size_t off = 0;
  float* segsum = (float*)(ws + off);
  off += (size_t)B_SZ * NSEG * D_SZ * sizeof(float);            // 128 KiB
  float* csum = (float*)(ws + off);
  off += (size_t)B_SZ * NCHUNK * D_SZ * sizeof(float);          // 4 MiB
  unsigned short* wfcb = (unsigned short*)(ws + off);
  off += (size_t)D_SZ * H_SZ * sizeof(unsigned short);          // 8 MiB
  unsigned short* wprojb = (unsigned short*)(ws + off);
  off += (size_t)H_SZ * D_SZ * sizeof(unsigned short);          // 8 MiB
  unsigned short* h2 = (unsigned short*)(ws + off);
  off += (size_t)B_SZ * T_SZ * D_SZ * sizeof(unsigned short);   // 32 MiB
  unsigned short* act = (unsigned short*)(ws + off);            // slice buffer

  const int M = B_SZ * T_SZ;                       // 16384
  const size_t tileBytes = 256ull * H_SZ * sizeof(unsigned short);  // 2 MiB
  size_t avail = (ws_size > off) ? (ws_size - off) : 0;
  int sliceTiles = (int)(avail / tileBytes);
  if (sliceTiles < 1) sliceTiles = 1;              // last-resort (ws too small)
  int sliceM = sliceTiles * 256;
  if (sliceM > M) sliceM = M;

  attn_phase1<<<B_SZ * NCHUNK, 256, 0, stream>>>(x, lengths, ln1_w, out, csum);
  seg_scan<<<B_SZ * NSEG * (D_SZ / 256), 256, 0, stream>>>(csum, segsum);
  seg_apply<<<B_SZ * NSEG * (D_SZ / 256), 256, 0, stream>>>(csum, segsum);
  attn_phase2_ln2<<<B_SZ * T_SZ, 256, 0, stream>>>(out, csum, lengths, ln2_w, h2);
  transpose_f32_to_bf16<<<dim3(H_SZ / 32, D_SZ / 32), 256, 0, stream>>>(
      Wfc, wfcb, D_SZ, H_SZ);
  transpose_f32_to_bf16<<<dim3(D_SZ / 32, H_SZ / 32), 256, 0, stream>>>(
      Wproj, wprojb, H_SZ, D_SZ);

  for (int m0 = 0; m0 < M; m0 += sliceM) {
    int rows = (M - m0 < sliceM) ? (M - m0) : sliceM;
    int r1 = rows / 256;
    // act = bf16(gelu(h2[m0:m0+rows] @ Wfc))       grid = 16*r1 (%8==0)
    gemm256_bt<<<dim3((H_SZ / 256) * r1), 512, 131072, stream>>>(
        h2 + (size_t)m0 * D_SZ, wfcb, H_SZ, D_SZ, H_SZ / 256,
        nullptr, nullptr, act, 0);
    // out[m0:m0+rows] += act @ Wproj               grid = 4*r1
    gemm256_bt<<<dim3((D_SZ / 256) * r1), 512, 131072, stream>>>(
        act, wprojb, D_SZ, H_SZ, D_SZ / 256,
        out + (size_t)m0 * D_SZ, out + (size_t)m0 * D_SZ, nullptr, 1);
  }
}